// Round 3
// baseline (809.971 us; speedup 1.0000x reference)
//
#include <hip/hip_runtime.h>
#include <hip/hip_bf16.h>
#include <cstdint>
#include <cstddef>

// B=2, L=2048, D=1024, F=4096, E=8, K=2
#define B_ 2
#define L_ 2048
#define D_ 1024
#define F_ 4096
#define E_ 8
#define NTOK 4096
#define MAXROWS 9216   // sum over experts of pad128(n_e) <= 8192 + 8*127
#define MAXMT 72       // MAXROWS / 128

typedef __hip_bfloat16 bf16;
typedef __attribute__((ext_vector_type(8))) short short8;
typedef __attribute__((ext_vector_type(4))) float floatx4;

typedef const __attribute__((address_space(1))) uint32_t* gptr_t;
typedef __attribute__((address_space(3))) uint32_t* lptr_t;

__device__ __forceinline__ void async_load16(const bf16* gp, bf16* lp) {
    __builtin_amdgcn_global_load_lds((gptr_t)(const void*)gp, (lptr_t)(void*)lp, 16, 0, 0);
}

__device__ __forceinline__ uint16_t bfbits(bf16 h) {
    union { bf16 b; uint16_t u; } v; v.b = h; return v.u;
}
__device__ __forceinline__ uint32_t pack2(float a, float b) {
    return (uint32_t)bfbits(__float2bfloat16(a)) | ((uint32_t)bfbits(__float2bfloat16(b)) << 16);
}
__device__ __forceinline__ float ublo(uint32_t u){ return __uint_as_float(u << 16); }
__device__ __forceinline__ float ubhi(uint32_t u){ return __uint_as_float(u & 0xffff0000u); }

// tanh-form GELU: x * sigmoid(2*sqrt(2/pi)*(x + 0.044715 x^3)); max |err| vs exact ~3e-4
__device__ __forceinline__ float fast_gelu(float x) {
    float x2 = x * x;
    float z = x * fmaf(0.1029432f, x2, 2.3022081f);   // 2*log2(e)*0.7978845608*(1, 0.044715)
    z = fminf(z, 120.f);                               // avoid inf/inf
    float u = __builtin_amdgcn_exp2f(z);
    return x * u * __builtin_amdgcn_rcpf(1.f + u);
}

// ---------------- gating: 256 blocks x 256 thr, 16 tokens/block (4/wave) ----------------
__global__ __launch_bounds__(256) void gate_kernel(
    const float* __restrict__ x, const float* __restrict__ Wg,
    const float* __restrict__ bg, float* __restrict__ psum_pad,
    uint32_t* __restrict__ top_ids, float* __restrict__ top_w)
{
    __shared__ float psum_l[E_];
    int t = threadIdx.x;
    if (t < E_) psum_l[t] = 0.f;
    __syncthreads();

    int wave = t >> 6, lane = t & 63;
    for (int j = 0; j < 4; ++j) {
        int token = blockIdx.x * 16 + wave * 4 + j;
        const float* xr = x + (size_t)token * D_;

        float acc[E_];
#pragma unroll
        for (int e = 0; e < E_; ++e) acc[e] = 0.f;
#pragma unroll
        for (int i = 0; i < 4; ++i) {
            int d = lane * 4 + 256 * i;
            float4 xv = *(const float4*)(xr + d);
            const float* xs = &xv.x;
#pragma unroll
            for (int jj = 0; jj < 4; ++jj) {
                const float4* wr4 = (const float4*)(Wg + (size_t)(d + jj) * E_);
                float4 wa = wr4[0], wb = wr4[1];
                float xvj = xs[jj];
                acc[0] += xvj * wa.x;  acc[1] += xvj * wa.y;
                acc[2] += xvj * wa.z;  acc[3] += xvj * wa.w;
                acc[4] += xvj * wb.x;  acc[5] += xvj * wb.y;
                acc[6] += xvj * wb.z;  acc[7] += xvj * wb.w;
            }
        }
#pragma unroll
        for (int off = 32; off >= 1; off >>= 1) {
#pragma unroll
            for (int e = 0; e < E_; ++e) acc[e] += __shfl_xor(acc[e], off, 64);
        }
        if (lane == 0) {
            float s[E_];
#pragma unroll
            for (int e = 0; e < E_; ++e) s[e] = acc[e] + bg[e];
            int i0 = 0;
#pragma unroll
            for (int e = 1; e < E_; ++e) if (s[e] > s[i0]) i0 = e;
            int i1 = -1;
#pragma unroll
            for (int e = 0; e < E_; ++e) {
                if (e == i0) continue;
                if (i1 < 0 || s[e] > s[i1]) i1 = e;
            }
            float e1 = expf(s[i1] - s[i0]);
            float w0 = 1.f / (1.f + e1);
            float w1 = e1 * w0;
            top_ids[token] = (uint32_t)i0 | ((uint32_t)i1 << 8);
            top_w[token]        = w0;
            top_w[NTOK + token] = w1;

            float mx = s[i0], p[E_], sum = 0.f;
#pragma unroll
            for (int e = 0; e < E_; ++e) { p[e] = expf(s[e] - mx); sum += p[e]; }
            float inv = 1.f / sum;
#pragma unroll
            for (int e = 0; e < E_; ++e) atomicAdd(&psum_l[e], p[e] * inv);
        }
    }
    __syncthreads();
    if (t < E_) atomicAdd(&psum_pad[t * 32], psum_l[t]);
}

// ---------------- deterministic per-expert compaction + inverse index ----------------
__global__ __launch_bounds__(256) void compact_kernel(
    const uint32_t* __restrict__ top_ids, const float* __restrict__ top_w,
    int* __restrict__ cnt, int* __restrict__ tok_list, float* __restrict__ w_list,
    int* __restrict__ rowid)
{
    int e = blockIdx.x;
    int t = threadIdx.x, wave = t >> 6, lane = t & 63;
    __shared__ int wcnt[4];
    int base = 0;
    for (int r0 = 0; r0 < NTOK; r0 += 256) {
        int token = r0 + t;
        uint32_t ids = top_ids[token];
        int slot = -1;
        if ((int)(ids & 255u) == e) slot = 0;
        else if ((int)((ids >> 8) & 255u) == e) slot = 1;
        unsigned long long mask = __ballot(slot >= 0);
        int lpos = __popcll(mask & ((1ull << lane) - 1ull));
        if (lane == 0) wcnt[wave] = (int)__popcll(mask);
        __syncthreads();
        int woff = 0, tot = 0;
#pragma unroll
        for (int w2 = 0; w2 < 4; ++w2) { if (w2 < wave) woff += wcnt[w2]; tot += wcnt[w2]; }
        if (slot >= 0) {
            int pos = base + woff + lpos;
            tok_list[e*NTOK + pos] = token;
            w_list[e*NTOK + pos]   = top_w[slot*NTOK + token];
            rowid[slot*NTOK + token] = (e << 13) | pos;   // inverse index for combine
        }
        base += tot;
        __syncthreads();
    }
    if (t == 0) cnt[e] = base;
}

// ---------------- finalize: padded prefix offsets + loss + gemm mtile map ----------------
// mt_map[g] = (e << 8) | local_mtile for every 128-row tile across all experts.
// mt_hdr[0] = total mtiles, mt_hdr[1] = balanced per-XCD chunk size ceil(nmt/8).
__global__ void finalize_gate_kernel(const int* __restrict__ cnt, const float* __restrict__ psum_pad,
                                     int* __restrict__ off, float* __restrict__ loss_out,
                                     int* __restrict__ mt_map, int* __restrict__ mt_hdr)
{
    int o = 0; float Ls = 0.f; int g = 0;
    for (int e = 0; e < E_; ++e) {
        off[e] = o;
        int mt = (cnt[e] + 127) >> 7;
        for (int m = 0; m < mt; ++m) mt_map[g++] = (e << 8) | m;
        o += mt << 7;
        Ls += (float)cnt[e] * psum_pad[e * 32];
    }
    mt_hdr[0] = g;
    mt_hdr[1] = (g + 7) >> 3;
    loss_out[0] = (float)E_ * Ls / ((float)NTOK * (float)NTOK);
}

// ---------------- weight transpose+convert v3: LDS row-pair packing ----------------
// [R][C] f32 -> [C][R] bf16 per expert, 64x64 tiles.
__global__ __launch_bounds__(256) void transpose_bf16_kernel(
    const float* __restrict__ in, bf16* __restrict__ outp, int R, int C)
{
    int tilesR = R >> 6, tilesC = C >> 6;
    int per = tilesR * tilesC;
    int bx = blockIdx.x;
    int e  = bx / per; int r2 = bx % per;
    int tr = r2 / tilesC, tc = r2 % tilesC;
    int r0 = tr << 6, c0 = tc << 6;
    const float* ip = in  + (size_t)e * R * C;
    bf16*        op = outp + (size_t)e * R * C;

    __shared__ uint32_t T[64][36];   // [col][row-pair], padded stride
    int t = threadIdx.x;
    int rp = t >> 4;          // 0..15
    int c4 = (t & 15) * 4;

#pragma unroll
    for (int it = 0; it < 2; ++it) {
        int pr = rp + 16 * it;    // pair index 0..31
        const float* p = ip + (size_t)(r0 + 2*pr) * C + c0 + c4;
        float4 a = *(const float4*)(p);
        float4 b = *(const float4*)(p + C);
        T[c4+0][pr] = pack2(a.x, b.x);
        T[c4+1][pr] = pack2(a.y, b.y);
        T[c4+2][pr] = pack2(a.z, b.z);
        T[c4+3][pr] = pack2(a.w, b.w);
    }
    __syncthreads();

    int s     = t & 7;        // 16B segment within output row
    int cbase = t >> 3;       // 0..31
#pragma unroll
    for (int pass = 0; pass < 2; ++pass) {
        int cc = cbase + 32 * pass;
        uint4 u = *(const uint4*)&T[cc][4*s];
        *(uint4*)(op + (size_t)(c0 + cc) * R + r0 + 8*s) = u;
    }
}

// ---------------- gather tokens into compacted bf16 A-matrix ----------------
__global__ __launch_bounds__(256) void gather_kernel(
    const float* __restrict__ x, const int* __restrict__ cnt, const int* __restrict__ off,
    const int* __restrict__ tok_list, bf16* __restrict__ Xg)
{
    int bx = blockIdx.x;
    int e  = bx >> 12;
    int i  = bx & 4095;
    if (i >= cnt[e]) return;
    int tok = tok_list[e*NTOK + i];
    size_t row = (size_t)(off[e] + i);
    int t = threadIdx.x;
    float4 v = *(const float4*)(x + (size_t)tok * D_ + t*4);
    uint2 uu;
    uu.x = pack2(v.x, v.y);
    uu.y = pack2(v.z, v.w);
    *(uint2*)(Xg + row * D_ + t*4) = uu;
}

// ============ GEMM1: H = gelu(Xg @ W1 + b1), bf16 out ============
// v4: counted-vmcnt deep pipeline (T4). 4 LDS buffers, distance-3 prefetch,
// raw s_barrier, s_waitcnt vmcnt(16) -> tiles i+1,i+2 stay in flight across barriers.
// XCD-chunked mtile mapping (same as gemm2) for A-panel L2 locality.
__global__ __launch_bounds__(256) void gemm1_kernel(
    const bf16* __restrict__ Xg, const bf16* __restrict__ W1t,
    const float* __restrict__ b1, const int* __restrict__ cnt,
    const int* __restrict__ off, const int* __restrict__ mt_map,
    const int* __restrict__ mt_hdr, bf16* __restrict__ H)
{
    int bx = blockIdx.x;
    int k  = bx & 7;          // XCD id under round-robin dispatch
    int j  = bx >> 3;         // 0..287 position within XCD
    int jj = j >> 5;          // chunk-local mtile 0..8
    int ntile = j & 31;
    int nmt = mt_hdr[0], qc = mt_hdr[1];
    if (jj >= qc) return;
    int mt = k * qc + jj;
    if (mt >= nmt) return;
    int em = mt_map[mt];
    int e = em >> 8, mtile = em & 255;
    int row0 = off[e] + mtile * 128;
    int f0 = ntile * 128;

    __shared__ bf16 As[4][128*64];
    __shared__ bf16 Bs[4][128*64];

    int t = threadIdx.x;
    int wave = t >> 6, lane = t & 63;
    int wm = wave & 1, wn = wave >> 1;
    int q = lane >> 4, ln = lane & 15;
    int sm = lane >> 3, sc = lane & 7;

    const bf16* Abase = Xg  + (size_t)row0 * D_;
    const bf16* Bbase = W1t + ((size_t)e * F_ + f0) * D_;

    int g0 = wave*4;
    auto stage = [&](int b, int kt) {
#pragma unroll
        for (int i = 0; i < 4; ++i) {
            int g = g0 + i;
            int m = g*8 + sm;
            int ca = sc ^ (m & 7);
            async_load16(Abase + (size_t)m * D_ + kt + ca*8, &As[b][g*512]);
            async_load16(Bbase + (size_t)m * D_ + kt + ca*8, &Bs[b][g*512]);
        }
    };

    floatx4 acc[4][4];
#pragma unroll
    for (int mt2 = 0; mt2 < 4; ++mt2)
#pragma unroll
        for (int nt = 0; nt < 4; ++nt) acc[mt2][nt] = {0.f, 0.f, 0.f, 0.f};

    auto compute = [&](int b) {
#pragma unroll
        for (int kk = 0; kk < 2; ++kk) {
            short8 av[4], bv[4];
#pragma unroll
            for (int mt2 = 0; mt2 < 4; ++mt2) {
                int r = wm*64 + mt2*16 + ln;
                int cs = (kk*4 + q) ^ (r & 7);
                av[mt2] = *(const short8*)&As[b][r*64 + cs*8];
            }
#pragma unroll
            for (int nt = 0; nt < 4; ++nt) {
                int r = wn*64 + nt*16 + ln;
                int cs = (kk*4 + q) ^ (r & 7);
                bv[nt] = *(const short8*)&Bs[b][r*64 + cs*8];
            }
#pragma unroll
            for (int mt2 = 0; mt2 < 4; ++mt2)
#pragma unroll
                for (int nt = 0; nt < 4; ++nt)
                    acc[mt2][nt] = __builtin_amdgcn_mfma_f32_16x16x32_bf16(av[mt2], bv[nt], acc[mt2][nt], 0, 0, 0);
        }
    };

    const int NT = D_ / 64;   // 16
    stage(0, 0); stage(1, 64); stage(2, 128);          // 24 loads/wave in flight
    for (int i = 0; i < NT - 3; ++i) {
        asm volatile("s_waitcnt vmcnt(16)" ::: "memory");   // tile i resident
        __builtin_amdgcn_s_barrier();                       // all waves: tile i in, comp(i-1) done
        __builtin_amdgcn_sched_barrier(0);
        stage((i + 3) & 3, (i + 3) * 64);                   // overwrites buf of tile i-1
        compute(i & 3);
    }
    asm volatile("s_waitcnt vmcnt(16)" ::: "memory");
    __builtin_amdgcn_s_barrier();
    __builtin_amdgcn_sched_barrier(0);
    compute((NT - 3) & 3);
    asm volatile("s_waitcnt vmcnt(8)" ::: "memory");
    __builtin_amdgcn_s_barrier();
    __builtin_amdgcn_sched_barrier(0);
    compute((NT - 2) & 3);
    asm volatile("s_waitcnt vmcnt(0)" ::: "memory");
    __builtin_amdgcn_s_barrier();
    __builtin_amdgcn_sched_barrier(0);
    compute((NT - 1) & 3);

#pragma unroll
    for (int nt = 0; nt < 4; ++nt) {
        int f = f0 + wn*64 + nt*16 + ln;
        float b1v = b1[(size_t)e * F_ + f];
#pragma unroll
        for (int mt2 = 0; mt2 < 4; ++mt2) {
            int rl = wm*64 + mt2*16 + q*4;
#pragma unroll
            for (int r = 0; r < 4; ++r) {
                float v = acc[mt2][nt][r] + b1v;
                H[(size_t)(row0 + rl + r) * F_ + f] = __float2bfloat16(fast_gelu(v));
            }
        }
    }
}

// ============ GEMM2: Y[row] = H @ W2 + b2 (bf16, plain stores; no atomics) ============
// v4: counted-vmcnt deep pipeline (T4) + XCD-chunked block remap (kept from v3).
__global__ __launch_bounds__(256) void gemm2_kernel(
    const bf16* __restrict__ H, const bf16* __restrict__ W2t,
    const float* __restrict__ b2, const int* __restrict__ cnt, const int* __restrict__ off,
    const int* __restrict__ mt_map, const int* __restrict__ mt_hdr,
    bf16* __restrict__ Y)
{
    int bx = blockIdx.x;
    int k  = bx & 7;          // XCD id under round-robin dispatch
    int j  = bx >> 3;         // 0..71 position within XCD
    int jj = j >> 3;          // chunk-local mtile index 0..8
    int ntile = j & 7;
    int nmt = mt_hdr[0], qc = mt_hdr[1];
    if (jj >= qc) return;
    int mt = k * qc + jj;     // contiguous chunk per XCD
    if (mt >= nmt) return;
    int em = mt_map[mt];
    int e = em >> 8, mtile = em & 255;
    int n = cnt[e];
    int row0 = off[e] + mtile * 128;
    int d0 = ntile * 128;

    __shared__ bf16 As[4][128*64];
    __shared__ bf16 Bs[4][128*64];

    int t = threadIdx.x;
    int wave = t >> 6, lane = t & 63;
    int wm = wave & 1, wn = wave >> 1;
    int q = lane >> 4, ln = lane & 15;
    int sm = lane >> 3, sc = lane & 7;

    const bf16* Abase = H   + (size_t)row0 * F_;
    const bf16* Bbase = W2t + ((size_t)e * D_ + d0) * F_;

    int g0 = wave*4;
    auto stage = [&](int b, int kt) {
#pragma unroll
        for (int i = 0; i < 4; ++i) {
            int g = g0 + i;
            int m = g*8 + sm;
            int ca = sc ^ (m & 7);
            async_load16(Abase + (size_t)m * F_ + kt + ca*8, &As[b][g*512]);
            async_load16(Bbase + (size_t)m * F_ + kt + ca*8, &Bs[b][g*512]);
        }
    };

    floatx4 acc[4][4];
#pragma unroll
    for (int mt2 = 0; mt2 < 4; ++mt2)
#pragma unroll
        for (int nt = 0; nt < 4; ++nt) acc[mt2][nt] = {0.f, 0.f, 0.f, 0.f};

    auto compute = [&](int b) {
#pragma unroll
        for (int kk = 0; kk < 2; ++kk) {
            short8 av[4], bv[4];
#pragma unroll
            for (int mt2 = 0; mt2 < 4; ++mt2) {
                int r = wm*64 + mt2*16 + ln;
                int cs = (kk*4 + q) ^ (r & 7);
                av[mt2] = *(const short8*)&As[b][r*64 + cs*8];
            }
#pragma unroll
            for (int nt = 0; nt < 4; ++nt) {
                int r = wn*64 + nt*16 + ln;
                int cs = (kk*4 + q) ^ (r & 7);
                bv[nt] = *(const short8*)&Bs[b][r*64 + cs*8];
            }
#pragma unroll
            for (int mt2 = 0; mt2 < 4; ++mt2)
#pragma unroll
                for (int nt = 0; nt < 4; ++nt)
                    acc[mt2][nt] = __builtin_amdgcn_mfma_f32_16x16x32_bf16(av[mt2], bv[nt], acc[mt2][nt], 0, 0, 0);
        }
    };

    const int NT = F_ / 64;   // 64
    stage(0, 0); stage(1, 64); stage(2, 128);          // 24 loads/wave in flight
    for (int i = 0; i < NT - 3; ++i) {
        asm volatile("s_waitcnt vmcnt(16)" ::: "memory");   // tile i resident; i+1,i+2 in flight
        __builtin_amdgcn_s_barrier();
        __builtin_amdgcn_sched_barrier(0);
        stage((i + 3) & 3, (i + 3) * 64);                   // overwrites buf of tile i-1
        compute(i & 3);
    }
    asm volatile("s_waitcnt vmcnt(16)" ::: "memory");
    __builtin_amdgcn_s_barrier();
    __builtin_amdgcn_sched_barrier(0);
    compute((NT - 3) & 3);
    asm volatile("s_waitcnt vmcnt(8)" ::: "memory");
    __builtin_amdgcn_s_barrier();
    __builtin_amdgcn_sched_barrier(0);
    compute((NT - 2) & 3);
    asm volatile("s_waitcnt vmcnt(0)" ::: "memory");
    __builtin_amdgcn_s_barrier();
    __builtin_amdgcn_sched_barrier(0);
    compute((NT - 1) & 3);

    float b2v[4];
#pragma unroll
    for (int nt = 0; nt < 4; ++nt)
        b2v[nt] = b2[(size_t)e * D_ + d0 + wn*64 + nt*16 + ln];

#pragma unroll
    for (int mt2 = 0; mt2 < 4; ++mt2) {
#pragma unroll
        for (int r = 0; r < 4; ++r) {
            int loc = wm*64 + mt2*16 + q*4 + r;
            int i = mtile*128 + loc;
            if (i < n) {
                bf16* yp = Y + (size_t)(row0 + loc) * D_ + d0;
#pragma unroll
                for (int nt = 0; nt < 4; ++nt)
                    yp[wn*64 + nt*16 + ln] = __float2bfloat16(acc[mt2][nt][r] + b2v[nt]);
            }
        }
    }
}

// ---------------- combine: out[tok] = w0*Y[row0] + w1*Y[row1] ----------------
__global__ __launch_bounds__(256) void combine_kernel(
    const bf16* __restrict__ Y, const int* __restrict__ rowid,
    const float* __restrict__ top_w, const int* __restrict__ off,
    float* __restrict__ out)
{
    int tok = blockIdx.x;
    int t = threadIdx.x;
    int v0 = rowid[tok], v1 = rowid[NTOK + tok];
    float w0 = top_w[tok], w1 = top_w[NTOK + tok];
    size_t r0 = (size_t)(off[v0 >> 13] + (v0 & 8191));
    size_t r1 = (size_t)(off[v1 >> 13] + (v1 & 8191));
    uint2 a = *(const uint2*)(Y + r0 * D_ + t*4);
    uint2 b = *(const uint2*)(Y + r1 * D_ + t*4);
    float4 o;
    o.x = w0 * ublo(a.x) + w1 * ublo(b.x);
    o.y = w0 * ubhi(a.x) + w1 * ubhi(b.x);
    o.z = w0 * ublo(a.y) + w1 * ublo(b.y);
    o.w = w0 * ubhi(a.y) + w1 * ubhi(b.y);
    *(float4*)(out + (size_t)tok * D_ + t*4) = o;
}

extern "C" void kernel_launch(void* const* d_in, const int* in_sizes, int n_in,
                              void* d_out, int out_size, void* d_ws, size_t ws_size,
                              hipStream_t stream)
{
    const float* x  = (const float*)d_in[0];
    const float* Wg = (const float*)d_in[1];
    const float* bg = (const float*)d_in[2];
    const float* W1 = (const float*)d_in[3];
    const float* b1 = (const float*)d_in[4];
    const float* W2 = (const float*)d_in[5];
    const float* b2 = (const float*)d_in[6];
    float* out = (float*)d_out;

    char* ws = (char*)d_ws;
    int*      cnt      = (int*)(ws + 0);
    int*      off      = (int*)(ws + 128);
    int*      mt_map   = (int*)(ws + 256);               // 72 ints, 256..544
    int*      mt_hdr   = (int*)(ws + 576);               // 2 ints
    float*    psum_pad = (float*)(ws + 1024);
    uint32_t* top_ids  = (uint32_t*)(ws + 8192);
    float*    top_w    = (float*)(ws + 8192 + 16384);
    int*      tok_list = (int*)(ws + 65536);
    float*    w_list   = (float*)(ws + 65536 + 131072);
    int*      rowid    = (int*)(ws + 327680);            // [2][NTOK]
    size_t o = 1u << 20;
    bf16*  W1t = (bf16*)(ws + o);  o += (size_t)E_ * D_ * F_ * 2;   // 64 MB
    bf16*  W2t = (bf16*)(ws + o);  o += (size_t)E_ * F_ * D_ * 2;   // 64 MB
    bf16*  Xg  = (bf16*)(ws + o);  o += (size_t)MAXROWS * D_ * 2;   // 18.9 MB
    bf16*  H   = (bf16*)(ws + o);                                    // 75.5 MB
    bf16*  Y   = Xg;   // alias: Xg dead after gemm1; Y written by gemm2 (same size/shape)

    hipMemsetAsync(ws + 1024, 0, 1024, stream);   // psum_pad

    transpose_bf16_kernel<<<E_ * 16 * 64, 256, 0, stream>>>(W1, W1t, D_, F_);  // -> [E][F][D]
    transpose_bf16_kernel<<<E_ * 64 * 16, 256, 0, stream>>>(W2, W2t, F_, D_);  // -> [E][D][F]

    gate_kernel<<<256, 256, 0, stream>>>(x, Wg, bg, psum_pad, top_ids, top_w);
    compact_kernel<<<E_, 256, 0, stream>>>(top_ids, top_w, cnt, tok_list, w_list, rowid);
    finalize_gate_kernel<<<1, 1, 0, stream>>>(cnt, psum_pad, off, out + (size_t)NTOK * D_, mt_map, mt_hdr);
    gather_kernel<<<E_ * 4096, 256, 0, stream>>>(x, cnt, off, tok_list, Xg);

    gemm1_kernel<<<MAXMT * 32, 256, 0, stream>>>(Xg, W1t, b1, cnt, off, mt_map, mt_hdr, H);
    gemm2_kernel<<<MAXMT * 8, 256, 0, stream>>>(H, W2t, b2, cnt, off, mt_map, mt_hdr, Y);
    combine_kernel<<<NTOK, 256, 0, stream>>>(Y, rowid, top_w, off, out);
}

// Round 4
// 627.535 us; speedup vs baseline: 1.2907x; 1.2907x over previous
//
#include <hip/hip_runtime.h>
#include <hip/hip_bf16.h>
#include <cstdint>
#include <cstddef>

// B=2, L=2048, D=1024, F=4096, E=8, K=2
#define B_ 2
#define L_ 2048
#define D_ 1024
#define F_ 4096
#define E_ 8
#define NTOK 4096
#define MAXROWS 9216   // sum over experts of pad128(n_e) <= 8192 + 8*127
#define MAXMT 72       // MAXROWS / 128

typedef __hip_bfloat16 bf16;
typedef __attribute__((ext_vector_type(8))) short short8;
typedef __attribute__((ext_vector_type(4))) float floatx4;

typedef const __attribute__((address_space(1))) uint32_t* gptr_t;
typedef __attribute__((address_space(3))) uint32_t* lptr_t;

__device__ __forceinline__ void async_load16(const bf16* gp, bf16* lp) {
    __builtin_amdgcn_global_load_lds((gptr_t)(const void*)gp, (lptr_t)(void*)lp, 16, 0, 0);
}

__device__ __forceinline__ uint16_t bfbits(bf16 h) {
    union { bf16 b; uint16_t u; } v; v.b = h; return v.u;
}
__device__ __forceinline__ uint32_t pack2(float a, float b) {
    return (uint32_t)bfbits(__float2bfloat16(a)) | ((uint32_t)bfbits(__float2bfloat16(b)) << 16);
}
__device__ __forceinline__ float ublo(uint32_t u){ return __uint_as_float(u << 16); }
__device__ __forceinline__ float ubhi(uint32_t u){ return __uint_as_float(u & 0xffff0000u); }

// tanh-form GELU: x * sigmoid(2*sqrt(2/pi)*(x + 0.044715 x^3)); max |err| vs exact ~3e-4
__device__ __forceinline__ float fast_gelu(float x) {
    float x2 = x * x;
    float z = x * fmaf(0.1029432f, x2, 2.3022081f);   // 2*log2(e)*0.7978845608*(1, 0.044715)
    z = fminf(z, 120.f);                               // avoid inf/inf
    float u = __builtin_amdgcn_exp2f(z);
    return x * u * __builtin_amdgcn_rcpf(1.f + u);
}

// ---------------- gating: 256 blocks x 256 thr, 16 tokens/block (4/wave) ----------------
__global__ __launch_bounds__(256) void gate_kernel(
    const float* __restrict__ x, const float* __restrict__ Wg,
    const float* __restrict__ bg, float* __restrict__ psum_pad,
    uint32_t* __restrict__ top_ids, float* __restrict__ top_w)
{
    __shared__ float psum_l[E_];
    int t = threadIdx.x;
    if (t < E_) psum_l[t] = 0.f;
    __syncthreads();

    int wave = t >> 6, lane = t & 63;
    for (int j = 0; j < 4; ++j) {
        int token = blockIdx.x * 16 + wave * 4 + j;
        const float* xr = x + (size_t)token * D_;

        float acc[E_];
#pragma unroll
        for (int e = 0; e < E_; ++e) acc[e] = 0.f;
#pragma unroll
        for (int i = 0; i < 4; ++i) {
            int d = lane * 4 + 256 * i;
            float4 xv = *(const float4*)(xr + d);
            const float* xs = &xv.x;
#pragma unroll
            for (int jj = 0; jj < 4; ++jj) {
                const float4* wr4 = (const float4*)(Wg + (size_t)(d + jj) * E_);
                float4 wa = wr4[0], wb = wr4[1];
                float xvj = xs[jj];
                acc[0] += xvj * wa.x;  acc[1] += xvj * wa.y;
                acc[2] += xvj * wa.z;  acc[3] += xvj * wa.w;
                acc[4] += xvj * wb.x;  acc[5] += xvj * wb.y;
                acc[6] += xvj * wb.z;  acc[7] += xvj * wb.w;
            }
        }
#pragma unroll
        for (int off = 32; off >= 1; off >>= 1) {
#pragma unroll
            for (int e = 0; e < E_; ++e) acc[e] += __shfl_xor(acc[e], off, 64);
        }
        if (lane == 0) {
            float s[E_];
#pragma unroll
            for (int e = 0; e < E_; ++e) s[e] = acc[e] + bg[e];
            int i0 = 0;
#pragma unroll
            for (int e = 1; e < E_; ++e) if (s[e] > s[i0]) i0 = e;
            int i1 = -1;
#pragma unroll
            for (int e = 0; e < E_; ++e) {
                if (e == i0) continue;
                if (i1 < 0 || s[e] > s[i1]) i1 = e;
            }
            float e1 = expf(s[i1] - s[i0]);
            float w0 = 1.f / (1.f + e1);
            float w1 = e1 * w0;
            top_ids[token] = (uint32_t)i0 | ((uint32_t)i1 << 8);
            top_w[token]        = w0;
            top_w[NTOK + token] = w1;

            float mx = s[i0], p[E_], sum = 0.f;
#pragma unroll
            for (int e = 0; e < E_; ++e) { p[e] = expf(s[e] - mx); sum += p[e]; }
            float inv = 1.f / sum;
#pragma unroll
            for (int e = 0; e < E_; ++e) atomicAdd(&psum_l[e], p[e] * inv);
        }
    }
    __syncthreads();
    if (t < E_) atomicAdd(&psum_pad[t * 32], psum_l[t]);
}

// ---------------- deterministic per-expert compaction + inverse index ----------------
__global__ __launch_bounds__(256) void compact_kernel(
    const uint32_t* __restrict__ top_ids, const float* __restrict__ top_w,
    int* __restrict__ cnt, int* __restrict__ tok_list, float* __restrict__ w_list,
    int* __restrict__ rowid)
{
    int e = blockIdx.x;
    int t = threadIdx.x, wave = t >> 6, lane = t & 63;
    __shared__ int wcnt[4];
    int base = 0;
    for (int r0 = 0; r0 < NTOK; r0 += 256) {
        int token = r0 + t;
        uint32_t ids = top_ids[token];
        int slot = -1;
        if ((int)(ids & 255u) == e) slot = 0;
        else if ((int)((ids >> 8) & 255u) == e) slot = 1;
        unsigned long long mask = __ballot(slot >= 0);
        int lpos = __popcll(mask & ((1ull << lane) - 1ull));
        if (lane == 0) wcnt[wave] = (int)__popcll(mask);
        __syncthreads();
        int woff = 0, tot = 0;
#pragma unroll
        for (int w2 = 0; w2 < 4; ++w2) { if (w2 < wave) woff += wcnt[w2]; tot += wcnt[w2]; }
        if (slot >= 0) {
            int pos = base + woff + lpos;
            tok_list[e*NTOK + pos] = token;
            w_list[e*NTOK + pos]   = top_w[slot*NTOK + token];
            rowid[slot*NTOK + token] = (e << 13) | pos;   // inverse index for combine
        }
        base += tot;
        __syncthreads();
    }
    if (t == 0) cnt[e] = base;
}

// ---------------- finalize: padded prefix offsets + loss + gemm mtile map ----------------
// mt_map[g] = (e << 8) | local_mtile for every 128-row tile across all experts.
// mt_hdr[0] = total mtiles, mt_hdr[1] = balanced per-XCD chunk size ceil(nmt/8).
__global__ void finalize_gate_kernel(const int* __restrict__ cnt, const float* __restrict__ psum_pad,
                                     int* __restrict__ off, float* __restrict__ loss_out,
                                     int* __restrict__ mt_map, int* __restrict__ mt_hdr)
{
    int o = 0; float Ls = 0.f; int g = 0;
    for (int e = 0; e < E_; ++e) {
        off[e] = o;
        int mt = (cnt[e] + 127) >> 7;
        for (int m = 0; m < mt; ++m) mt_map[g++] = (e << 8) | m;
        o += mt << 7;
        Ls += (float)cnt[e] * psum_pad[e * 32];
    }
    mt_hdr[0] = g;
    mt_hdr[1] = (g + 7) >> 3;
    loss_out[0] = (float)E_ * Ls / ((float)NTOK * (float)NTOK);
}

// ---------------- weight transpose+convert v3: LDS row-pair packing ----------------
// [R][C] f32 -> [C][R] bf16 per expert, 64x64 tiles.
__global__ __launch_bounds__(256) void transpose_bf16_kernel(
    const float* __restrict__ in, bf16* __restrict__ outp, int R, int C)
{
    int tilesR = R >> 6, tilesC = C >> 6;
    int per = tilesR * tilesC;
    int bx = blockIdx.x;
    int e  = bx / per; int r2 = bx % per;
    int tr = r2 / tilesC, tc = r2 % tilesC;
    int r0 = tr << 6, c0 = tc << 6;
    const float* ip = in  + (size_t)e * R * C;
    bf16*        op = outp + (size_t)e * R * C;

    __shared__ uint32_t T[64][36];   // [col][row-pair], padded stride
    int t = threadIdx.x;
    int rp = t >> 4;          // 0..15
    int c4 = (t & 15) * 4;

#pragma unroll
    for (int it = 0; it < 2; ++it) {
        int pr = rp + 16 * it;    // pair index 0..31
        const float* p = ip + (size_t)(r0 + 2*pr) * C + c0 + c4;
        float4 a = *(const float4*)(p);
        float4 b = *(const float4*)(p + C);
        T[c4+0][pr] = pack2(a.x, b.x);
        T[c4+1][pr] = pack2(a.y, b.y);
        T[c4+2][pr] = pack2(a.z, b.z);
        T[c4+3][pr] = pack2(a.w, b.w);
    }
    __syncthreads();

    int s     = t & 7;        // 16B segment within output row
    int cbase = t >> 3;       // 0..31
#pragma unroll
    for (int pass = 0; pass < 2; ++pass) {
        int cc = cbase + 32 * pass;
        uint4 u = *(const uint4*)&T[cc][4*s];
        *(uint4*)(op + (size_t)(c0 + cc) * R + r0 + 8*s) = u;
    }
}

// ---------------- gather tokens into compacted bf16 A-matrix ----------------
__global__ __launch_bounds__(256) void gather_kernel(
    const float* __restrict__ x, const int* __restrict__ cnt, const int* __restrict__ off,
    const int* __restrict__ tok_list, bf16* __restrict__ Xg)
{
    int bx = blockIdx.x;
    int e  = bx >> 12;
    int i  = bx & 4095;
    if (i >= cnt[e]) return;
    int tok = tok_list[e*NTOK + i];
    size_t row = (size_t)(off[e] + i);
    int t = threadIdx.x;
    float4 v = *(const float4*)(x + (size_t)tok * D_ + t*4);
    uint2 uu;
    uu.x = pack2(v.x, v.y);
    uu.y = pack2(v.z, v.w);
    *(uint2*)(Xg + row * D_ + t*4) = uu;
}

// ============ GEMM1: H = gelu(Xg @ W1 + b1), bf16 out ============
// R0 form (known-good): 128x128 tile, 32 KiB LDS, 2-barrier loop, 2048 active blocks
// (8/CU available) -> cross-block wave overlap pipelines it (m97/m114 regime).
__global__ __launch_bounds__(256) void gemm1_kernel(
    const bf16* __restrict__ Xg, const bf16* __restrict__ W1t,
    const float* __restrict__ b1, const int* __restrict__ cnt,
    const int* __restrict__ off, bf16* __restrict__ H)
{
    int bx = blockIdx.x;
    int e  = bx >> 10;
    int r2 = bx & 1023;
    int mtile = r2 >> 5, ntile = r2 & 31;
    int n = cnt[e];
    if (mtile * 128 >= n) return;
    int row0 = off[e] + mtile * 128;
    int f0 = ntile * 128;

    __shared__ bf16 As[128*64];
    __shared__ bf16 Bs[128*64];

    int t = threadIdx.x;
    int wave = t >> 6, lane = t & 63;
    int wm = wave & 1, wn = wave >> 1;
    int q = lane >> 4, ln = lane & 15;
    int sm = lane >> 3, sc = lane & 7;

    const bf16* Abase = Xg  + (size_t)row0 * D_;
    const bf16* Bbase = W1t + ((size_t)e * F_ + f0) * D_;

    floatx4 acc[4][4];
#pragma unroll
    for (int mt = 0; mt < 4; ++mt)
#pragma unroll
        for (int nt = 0; nt < 4; ++nt) acc[mt][nt] = {0.f, 0.f, 0.f, 0.f};

    for (int kt = 0; kt < D_; kt += 64) {
        __syncthreads();
#pragma unroll
        for (int i = 0; i < 4; ++i) {
            int g = wave*4 + i;
            int m = g*8 + sm;
            int ca = sc ^ (m & 7);
            async_load16(Abase + (size_t)m * D_ + kt + ca*8, &As[g*512]);
            async_load16(Bbase + (size_t)m * D_ + kt + ca*8, &Bs[g*512]);
        }
        __syncthreads();
#pragma unroll
        for (int kk = 0; kk < 2; ++kk) {
            short8 av[4], bv[4];
#pragma unroll
            for (int mt = 0; mt < 4; ++mt) {
                int r = wm*64 + mt*16 + ln;
                int cs = (kk*4 + q) ^ (r & 7);
                av[mt] = *(const short8*)&As[r*64 + cs*8];
            }
#pragma unroll
            for (int nt = 0; nt < 4; ++nt) {
                int r = wn*64 + nt*16 + ln;
                int cs = (kk*4 + q) ^ (r & 7);
                bv[nt] = *(const short8*)&Bs[r*64 + cs*8];
            }
#pragma unroll
            for (int mt = 0; mt < 4; ++mt)
#pragma unroll
                for (int nt = 0; nt < 4; ++nt)
                    acc[mt][nt] = __builtin_amdgcn_mfma_f32_16x16x32_bf16(av[mt], bv[nt], acc[mt][nt], 0, 0, 0);
        }
    }

#pragma unroll
    for (int nt = 0; nt < 4; ++nt) {
        int f = f0 + wn*64 + nt*16 + ln;
        float b1v = b1[(size_t)e * F_ + f];
#pragma unroll
        for (int mt = 0; mt < 4; ++mt) {
            int rl = wm*64 + mt*16 + q*4;
#pragma unroll
            for (int r = 0; r < 4; ++r) {
                float v = acc[mt][nt][r] + b1v;
                H[(size_t)(row0 + rl + r) * F_ + f] = __float2bfloat16(fast_gelu(v));
            }
        }
    }
}

// ============ GEMM2: Y[row] = H @ W2 + b2 (bf16, plain stores; no atomics) ============
// v5: 128x64 tiles (N-tile halved) -> 1024 active blocks (4/CU) + 24 KiB LDS
// (~6 blocks/CU cap). Restores the m97 occupancy regime: cross-block wave overlap
// does the pipelining (R3 showed explicit pipelining at 1 block/CU loses). Keeps the
// XCD-chunked mtile mapping (A-panel sharers co-resident on one XCD; FETCH stays
// compulsory-only ~120 MB). 2-barrier single-buffer loop = proven-correct inner loop.
// Wave grid 2m x 2n; per-wave output 64x32 (acc[4][2]).
__global__ __launch_bounds__(256) void gemm2_kernel(
    const bf16* __restrict__ H, const bf16* __restrict__ W2t,
    const float* __restrict__ b2, const int* __restrict__ cnt, const int* __restrict__ off,
    const int* __restrict__ mt_map, const int* __restrict__ mt_hdr,
    bf16* __restrict__ Y)
{
    int bx = blockIdx.x;
    int k  = bx & 7;          // XCD id under round-robin dispatch
    int j  = bx >> 3;         // position within XCD: 0..143
    int jj = j >> 4;          // chunk-local mtile index
    int ntile = j & 15;       // 16 ntiles of 64 cols
    int nmt = mt_hdr[0], qc = mt_hdr[1];
    if (jj >= qc) return;
    int mt = k * qc + jj;     // contiguous mtile chunk per XCD
    if (mt >= nmt) return;
    int em = mt_map[mt];
    int e = em >> 8, mtile = em & 255;
    int n = cnt[e];
    int row0 = off[e] + mtile * 128;
    int d0 = ntile * 64;

    __shared__ bf16 As[128*64];   // 16 KiB
    __shared__ bf16 Bs[64*64];    // 8 KiB

    int t = threadIdx.x;
    int wave = t >> 6, lane = t & 63;
    int wm = wave & 1, wn = wave >> 1;     // 2 (m) x 2 (n) wave grid
    int q = lane >> 4, ln = lane & 15;
    int sm = lane >> 3, sc = lane & 7;

    const bf16* Abase = H   + (size_t)row0 * F_;
    const bf16* Bbase = W2t + ((size_t)e * D_ + d0) * F_;

    floatx4 acc[4][2];
#pragma unroll
    for (int mt2 = 0; mt2 < 4; ++mt2)
#pragma unroll
        for (int nt = 0; nt < 2; ++nt) acc[mt2][nt] = {0.f, 0.f, 0.f, 0.f};

    for (int kt = 0; kt < F_; kt += 64) {
        __syncthreads();
        // A: 16 groups of 8 rows (4 per wave); B: 8 groups (2 per wave)
#pragma unroll
        for (int i = 0; i < 4; ++i) {
            int g = wave*4 + i;
            int m = g*8 + sm;
            int ca = sc ^ (m & 7);
            async_load16(Abase + (size_t)m * F_ + kt + ca*8, &As[g*512]);
        }
#pragma unroll
        for (int i = 0; i < 2; ++i) {
            int g = wave*2 + i;
            int m = g*8 + sm;
            int ca = sc ^ (m & 7);
            async_load16(Bbase + (size_t)m * F_ + kt + ca*8, &Bs[g*512]);
        }
        __syncthreads();
#pragma unroll
        for (int kk = 0; kk < 2; ++kk) {
            short8 av[4], bv[2];
#pragma unroll
            for (int mt2 = 0; mt2 < 4; ++mt2) {
                int r = wm*64 + mt2*16 + ln;
                int cs = (kk*4 + q) ^ (r & 7);
                av[mt2] = *(const short8*)&As[r*64 + cs*8];
            }
#pragma unroll
            for (int nt = 0; nt < 2; ++nt) {
                int r = wn*32 + nt*16 + ln;
                int cs = (kk*4 + q) ^ (r & 7);
                bv[nt] = *(const short8*)&Bs[r*64 + cs*8];
            }
#pragma unroll
            for (int mt2 = 0; mt2 < 4; ++mt2)
#pragma unroll
                for (int nt = 0; nt < 2; ++nt)
                    acc[mt2][nt] = __builtin_amdgcn_mfma_f32_16x16x32_bf16(av[mt2], bv[nt], acc[mt2][nt], 0, 0, 0);
        }
    }

    float b2v[2];
#pragma unroll
    for (int nt = 0; nt < 2; ++nt)
        b2v[nt] = b2[(size_t)e * D_ + d0 + wn*32 + nt*16 + ln];

#pragma unroll
    for (int mt2 = 0; mt2 < 4; ++mt2) {
#pragma unroll
        for (int r = 0; r < 4; ++r) {
            int loc = wm*64 + mt2*16 + q*4 + r;
            int i = mtile*128 + loc;
            if (i < n) {
                bf16* yp = Y + (size_t)(row0 + loc) * D_ + d0;
#pragma unroll
                for (int nt = 0; nt < 2; ++nt)
                    yp[wn*32 + nt*16 + ln] = __float2bfloat16(acc[mt2][nt][r] + b2v[nt]);
            }
        }
    }
}

// ---------------- combine: out[tok] = w0*Y[row0] + w1*Y[row1] ----------------
__global__ __launch_bounds__(256) void combine_kernel(
    const bf16* __restrict__ Y, const int* __restrict__ rowid,
    const float* __restrict__ top_w, const int* __restrict__ off,
    float* __restrict__ out)
{
    int tok = blockIdx.x;
    int t = threadIdx.x;
    int v0 = rowid[tok], v1 = rowid[NTOK + tok];
    float w0 = top_w[tok], w1 = top_w[NTOK + tok];
    size_t r0 = (size_t)(off[v0 >> 13] + (v0 & 8191));
    size_t r1 = (size_t)(off[v1 >> 13] + (v1 & 8191));
    uint2 a = *(const uint2*)(Y + r0 * D_ + t*4);
    uint2 b = *(const uint2*)(Y + r1 * D_ + t*4);
    float4 o;
    o.x = w0 * ublo(a.x) + w1 * ublo(b.x);
    o.y = w0 * ubhi(a.x) + w1 * ubhi(b.x);
    o.z = w0 * ublo(a.y) + w1 * ublo(b.y);
    o.w = w0 * ubhi(a.y) + w1 * ubhi(b.y);
    *(float4*)(out + (size_t)tok * D_ + t*4) = o;
}

extern "C" void kernel_launch(void* const* d_in, const int* in_sizes, int n_in,
                              void* d_out, int out_size, void* d_ws, size_t ws_size,
                              hipStream_t stream)
{
    const float* x  = (const float*)d_in[0];
    const float* Wg = (const float*)d_in[1];
    const float* bg = (const float*)d_in[2];
    const float* W1 = (const float*)d_in[3];
    const float* b1 = (const float*)d_in[4];
    const float* W2 = (const float*)d_in[5];
    const float* b2 = (const float*)d_in[6];
    float* out = (float*)d_out;

    char* ws = (char*)d_ws;
    int*      cnt      = (int*)(ws + 0);
    int*      off      = (int*)(ws + 128);
    int*      mt_map   = (int*)(ws + 256);               // 72 ints, 256..544
    int*      mt_hdr   = (int*)(ws + 576);               // 2 ints
    float*    psum_pad = (float*)(ws + 1024);
    uint32_t* top_ids  = (uint32_t*)(ws + 8192);
    float*    top_w    = (float*)(ws + 8192 + 16384);
    int*      tok_list = (int*)(ws + 65536);
    float*    w_list   = (float*)(ws + 65536 + 131072);
    int*      rowid    = (int*)(ws + 327680);            // [2][NTOK]
    size_t o = 1u << 20;
    bf16*  W1t = (bf16*)(ws + o);  o += (size_t)E_ * D_ * F_ * 2;   // 64 MB
    bf16*  W2t = (bf16*)(ws + o);  o += (size_t)E_ * F_ * D_ * 2;   // 64 MB
    bf16*  Xg  = (bf16*)(ws + o);  o += (size_t)MAXROWS * D_ * 2;   // 18.9 MB
    bf16*  H   = (bf16*)(ws + o);                                    // 75.5 MB
    bf16*  Y   = Xg;   // alias: Xg dead after gemm1; Y written by gemm2 (same size/shape)

    hipMemsetAsync(ws + 1024, 0, 1024, stream);   // psum_pad

    transpose_bf16_kernel<<<E_ * 16 * 64, 256, 0, stream>>>(W1, W1t, D_, F_);  // -> [E][F][D]
    transpose_bf16_kernel<<<E_ * 64 * 16, 256, 0, stream>>>(W2, W2t, F_, D_);  // -> [E][D][F]

    gate_kernel<<<256, 256, 0, stream>>>(x, Wg, bg, psum_pad, top_ids, top_w);
    compact_kernel<<<E_, 256, 0, stream>>>(top_ids, top_w, cnt, tok_list, w_list, rowid);
    finalize_gate_kernel<<<1, 1, 0, stream>>>(cnt, psum_pad, off, out + (size_t)NTOK * D_, mt_map, mt_hdr);
    gather_kernel<<<E_ * 4096, 256, 0, stream>>>(x, cnt, off, tok_list, Xg);

    gemm1_kernel<<<E_ * 32 * 32, 256, 0, stream>>>(Xg, W1t, b1, cnt, off, H);
    gemm2_kernel<<<MAXMT * 16, 256, 0, stream>>>(H, W2t, b2, cnt, off, mt_map, mt_hdr, Y);
    combine_kernel<<<NTOK, 256, 0, stream>>>(Y, rowid, top_w, off, out);
}